// Round 8
// baseline (309.069 us; speedup 1.0000x reference)
//
#include <hip/hip_runtime.h>
#include <cstdint>
#include <cstddef>

// RNNDec GRU rollout: N=4096, H=512, T=12. R8 = R5 core (gi16 3-plane, proven
// 295us) + vectorized k0 + direct-dot k3 (safe R6/R7 parts) + ONE hot-path
// experiment: k2 K-loop processes chunk PAIRS (BK=128/phase, 2 chunk regions,
// single-buffered 57KB LDS) -> 8 barriers instead of 16, 2x MFMA/ds_read per
// barrier. Slot+XOR LDS layout per sub-chunk identical to R5 (bank-safe).

typedef __attribute__((ext_vector_type(8))) _Float16 f16x8;
typedef __attribute__((ext_vector_type(4))) _Float16 f16x4;
typedef __attribute__((ext_vector_type(16))) float floatx16;

__device__ __forceinline__ float sigm_f(float v) { return 1.0f / (1.0f + __expf(-v)); }
__device__ __forceinline__ float tanh_f(float v) { return 2.0f / (1.0f + __expf(-2.0f * v)) - 1.0f; }

__device__ __forceinline__ void async16(void* lds, const void* g) {
    __builtin_amdgcn_global_load_lds(
        (const __attribute__((address_space(1))) void*)g,
        (__attribute__((address_space(3))) void*)lds, 16, 0, 0);
}

// ---------------- K0: casts + packing + a0 (vectorized) ----------------
__global__ __launch_bounds__(256) void k0_prep(
    const float* __restrict__ z, const float* __restrict__ x,
    const float* __restrict__ x0, const float* __restrict__ W_ia,
    const float* __restrict__ b_ia, const float* __restrict__ W_ih,
    const float* __restrict__ W_hh, const float* __restrict__ W_h0,
    const float* __restrict__ W_out, const float* __restrict__ b_hh,
    _Float16* __restrict__ zx16, _Float16* __restrict__ wcat16,
    _Float16* __restrict__ whh16, float* __restrict__ pk, float* __restrict__ xbuf)
{
    const int ZXV = 262144;            // 4096*256/4
    const int WCV = 131072;            // 2048*256/4
    const int WHV = 196608;            // 1536*512/4
    const int PKN = 512, XB = 8192;
    const int TOT = ZXV + WCV + WHV + PKN + XB;
    for (int g = blockIdx.x * 256 + threadIdx.x; g < TOT; g += gridDim.x * 256) {
        if (g < ZXV) {
            int i = g >> 6, k = (g & 63) << 2;
            float4 v = (k < 128) ? *(const float4*)(z + (size_t)i * 128 + k)
                                 : *(const float4*)(x + (size_t)i * 128 + (k - 128));
            f16x4 o = {(_Float16)v.x, (_Float16)v.y, (_Float16)v.z, (_Float16)v.w};
            *(f16x4*)(zx16 + (size_t)g * 4) = o;
        } else if (g < ZXV + WCV) {
            int j = (g - ZXV) << 2;
            int n = j >> 8, k = j & 255;
            float4 v;
            if (n < 512) {
                v = *(const float4*)(W_h0 + (size_t)n * 256 + k);
            } else {
                const float* p = W_ih + (size_t)(n - 512) * 258 + k;
                float2 a = *(const float2*)p, b = *(const float2*)(p + 2);
                v = make_float4(a.x, a.y, b.x, b.y);
            }
            f16x4 o = {(_Float16)v.x, (_Float16)v.y, (_Float16)v.z, (_Float16)v.w};
            *(f16x4*)(wcat16 + (size_t)j) = o;
        } else if (g < ZXV + WCV + WHV) {
            int j = (g - ZXV - WCV) << 2;
            float4 v = *(const float4*)(W_hh + (size_t)j);
            f16x4 o = {(_Float16)v.x, (_Float16)v.y, (_Float16)v.z, (_Float16)v.w};
            *(f16x4*)(whh16 + (size_t)j) = o;
        } else if (g < ZXV + WCV + WHV + PKN) {
            int jc = g - ZXV - WCV - WHV;
            float* o = pk + jc * 12;
            o[0] = W_ih[jc * 258 + 256];          o[1] = W_ih[jc * 258 + 257];
            o[2] = W_ih[(512 + jc) * 258 + 256];  o[3] = W_ih[(512 + jc) * 258 + 257];
            o[4] = W_ih[(1024 + jc) * 258 + 256]; o[5] = W_ih[(1024 + jc) * 258 + 257];
            o[6] = b_hh[jc]; o[7] = b_hh[512 + jc]; o[8] = b_hh[1024 + jc];
            o[9] = W_out[jc]; o[10] = W_out[512 + jc]; o[11] = 0.f;
        } else {
            int j = g - ZXV - WCV - WHV - PKN;
            int i = j >> 1, d = j & 1;
            float s = b_ia[d];
            #pragma unroll
            for (int k2 = 0; k2 < 4; k2++) s += x0[i * 4 + k2] * W_ia[d * 4 + k2];
            xbuf[j] = s;
        }
    }
}

// ---------------- K1: h0 (cols 0..511) + gi 3 planes (cols 512..2047) ----------------
__global__ __launch_bounds__(256) void k1_precompute(
    const _Float16* __restrict__ zx16, const _Float16* __restrict__ wcat16,
    const float* __restrict__ b_h0, const float* __restrict__ b_ih,
    _Float16* __restrict__ h16a, _Float16* __restrict__ gi16)
{
    __shared__ __align__(16) char smem[24576];
    const uint32_t BOFF = 0, AOFF = 8192;
    int tid = threadIdx.x;
    int w = tid >> 6, lane = tid & 63;
    int half = lane >> 5, l31 = lane & 31;
    int rsub = lane >> 3, csub = lane & 7;
    int Mb = blockIdx.x * 128, Nb = blockIdx.y * 64;

    const _Float16* gsrc[6];
    uint32_t ldso[6];
    #pragma unroll
    for (int j = 0; j < 6; j++) {
        int L = w + 4 * j;
        if (L < 16) {
            int r = L * 8 + rsub;
            gsrc[j] = zx16 + (size_t)(Mb + r) * 256 + ((csub ^ (r & 7)) << 3);
            ldso[j] = AOFF + (uint32_t)L * 1024;
        } else {
            int rb = (L - 16) * 8 + rsub;
            gsrc[j] = wcat16 + (size_t)(Nb + rb) * 256 + ((csub ^ (rb & 7)) << 3);
            ldso[j] = BOFF + (uint32_t)(L - 16) * 1024;
        }
    }

    floatx16 acc0 = {0,0,0,0,0,0,0,0,0,0,0,0,0,0,0,0};
    floatx16 acc1 = {0,0,0,0,0,0,0,0,0,0,0,0,0,0,0,0};

    for (int kc = 0; kc < 4; kc++) {
        #pragma unroll
        for (int j = 0; j < 6; j++) async16(smem + ldso[j], gsrc[j] + kc * 64);
        __syncthreads();
        #pragma unroll
        for (int ks = 0; ks < 4; ks++) {
            int ch = ks * 2 + half;
            int ar = (w << 5) | l31;
            f16x8 a = *(const f16x8*)(smem + AOFF + ((uint32_t)ar << 7) + ((uint32_t)(ch ^ (ar & 7)) << 4));
            uint32_t sw = (uint32_t)(ch ^ (l31 & 7)) << 4;
            f16x8 b0 = *(const f16x8*)(smem + BOFF + ((uint32_t)l31 << 7) + sw);
            f16x8 b1 = *(const f16x8*)(smem + BOFF + ((uint32_t)(32 + l31) << 7) + sw);
            acc0 = __builtin_amdgcn_mfma_f32_32x32x16_f16(a, b0, acc0, 0, 0, 0);
            acc1 = __builtin_amdgcn_mfma_f32_32x32x16_f16(a, b1, acc1, 0, 0, 0);
        }
        __syncthreads();
    }

    #pragma unroll
    for (int nt = 0; nt < 2; nt++) {
        int ncol = Nb + nt * 32 + l31;
        floatx16 acc = nt ? acc1 : acc0;
        #pragma unroll
        for (int reg = 0; reg < 16; reg++) {
            int row = (reg & 3) + 8 * (reg >> 2) + 4 * half;
            size_t i = (size_t)Mb + (w << 5) + row;
            float v = acc[reg];
            if (ncol < 512) {
                h16a[i * 512 + ncol] = (_Float16)(v + b_h0[ncol]);
            } else {
                int c = ncol - 512;
                int g = c >> 9, jc = c & 511;
                gi16[(size_t)g * 2097152 + i * 512 + jc] = (_Float16)(v + b_ih[c]);
            }
        }
    }
}

// ---------------- K2: one GRU step (paired-chunk K-loop, 8 barriers) ----------------
// Tile 128m x (32 jc x 3 gates). grid (32,16), 256 thr = 4 waves.
__global__ __launch_bounds__(256) void k2_step(
    int t,
    const _Float16* __restrict__ hin, _Float16* __restrict__ hout,
    const _Float16* __restrict__ whh16, const _Float16* __restrict__ gi16,
    const float* __restrict__ pk, const float* __restrict__ xbuf,
    float* __restrict__ partial, float* __restrict__ dout,
    const float* __restrict__ b_out)
{
    __shared__ __align__(16) char smem[58368];
    const uint32_t BOFF = 0;       // B: 2 regions x 12288 = 24576
    const uint32_t AOFF = 24576;   // A: 2 regions x 16384 = 32768 (ends 57344)
    const uint32_t PROD = 24576;   // epilogue overlay [128][32][2] f32 = 32768
    const uint32_t XS = 57344;     // [128][2] f32 = 1024 (ends 58368)
    int tid = threadIdx.x;
    int bx = blockIdx.x, by = blockIdx.y;
    int Mbase = bx * 128, Jbase = by * 32;
    int w = tid >> 6, lane = tid & 63;
    int half = lane >> 5, l31 = lane & 31;
    int rsub = lane >> 3, csub = lane & 7;
    float* xs = (float*)(smem + XS);  // [128][2]

    // staging: per 64-col chunk, A = 16 slots of 8 rows x 64 f16 (1 KB),
    // B = 12 slots (96 rows: g*32+jin). Region stride: A 16384, B 12288.
    const _Float16* gsrc[7];
    uint32_t ldso[7], rstr[7];
    #pragma unroll
    for (int j = 0; j < 7; j++) {
        int L = w + 4 * j;   // 0..27
        if (L < 16) {
            int r = L * 8 + rsub;
            gsrc[j] = hin + (size_t)(Mbase + r) * 512 + ((csub ^ (r & 7)) << 3);
            ldso[j] = AOFF + (uint32_t)L * 1024;
            rstr[j] = 16384;
        } else {
            int rb = (L - 16) * 8 + rsub;   // 0..95: rb = g*32 + jin
            int g = rb >> 5, jin = rb & 31;
            gsrc[j] = whh16 + (size_t)(g * 512 + Jbase + jin) * 512 + ((csub ^ (rb & 7)) << 3);
            ldso[j] = BOFF + (uint32_t)(L - 16) * 1024;
            rstr[j] = 12288;
        }
    }

    // prologue: x_t for this block's 128 samples (and write out_{t-1})
    {
        int i = tid >> 1, d = tid & 1;
        float v;
        if (t == 0) {
            v = xbuf[(size_t)(Mbase + i) * 2 + d];
        } else {
            const float4* p = (const float4*)(partial + ((size_t)(Mbase + i) * 2 + d) * 16);
            float4 a = p[0], b = p[1], c = p[2], e = p[3];
            v = b_out[d] + a.x + a.y + a.z + a.w + b.x + b.y + b.z + b.w
                         + c.x + c.y + c.z + c.w + e.x + e.y + e.z + e.w;
            if (by == 0) dout[((size_t)(Mbase + i) * 12 + (t - 1)) * 2 + d] = v;
        }
        xs[i * 2 + d] = v;
    }

    floatx16 accR = {0,0,0,0,0,0,0,0,0,0,0,0,0,0,0,0};
    floatx16 accZ = {0,0,0,0,0,0,0,0,0,0,0,0,0,0,0,0};
    floatx16 accN = {0,0,0,0,0,0,0,0,0,0,0,0,0,0,0,0};

    int ar = (w << 5) | l31;
    uint32_t abase = AOFF + (uint32_t)ar * 128;
    uint32_t aswz = (uint32_t)(ar & 7);
    uint32_t bswz = (uint32_t)(l31 & 7);

    for (int ph = 0; ph < 4; ph++) {
        #pragma unroll
        for (int cc = 0; cc < 2; cc++) {
            int kc = ph * 2 + cc;
            #pragma unroll
            for (int j = 0; j < 7; j++)
                async16(smem + ldso[j] + (uint32_t)cc * rstr[j], gsrc[j] + kc * 64);
        }
        __syncthreads();
        #pragma unroll
        for (int ks = 0; ks < 8; ks++) {
            int ch = ks * 2 + half;          // 0..15 over both sub-chunks
            uint32_t sub = (uint32_t)(ch >> 3);
            uint32_t chin = (uint32_t)(ch & 7);
            f16x8 a = *(const f16x8*)(smem + abase + sub * 16384 + ((chin ^ aswz) << 4));
            uint32_t sw = sub * 12288 + ((chin ^ bswz) << 4);
            f16x8 b0 = *(const f16x8*)(smem + BOFF + ((uint32_t)l31 << 7) + sw);
            f16x8 b1 = *(const f16x8*)(smem + BOFF + ((uint32_t)(32 + l31) << 7) + sw);
            f16x8 b2 = *(const f16x8*)(smem + BOFF + ((uint32_t)(64 + l31) << 7) + sw);
            accR = __builtin_amdgcn_mfma_f32_32x32x16_f16(a, b0, accR, 0, 0, 0);
            accZ = __builtin_amdgcn_mfma_f32_32x32x16_f16(a, b1, accZ, 0, 0, 0);
            accN = __builtin_amdgcn_mfma_f32_32x32x16_f16(a, b2, accN, 0, 0, 0);
        }
        __syncthreads();
    }

    // epilogue: gates + state update; out-partials in LDS (overlay A region)
    float* prod = (float*)(smem + PROD);  // [128][32][2] fp32 = 32 KB
    int jcg = Jbase + l31;
    const float4* pkp = (const float4*)(pk + (size_t)jcg * 12);
    float4 p0 = pkp[0], p1 = pkp[1], p2 = pkp[2];
    // p0={wxr0,wxr1,wxz0,wxz1} p1={wxn0,wxn1,bhr,bhz} p2={bhn,wo0,wo1,-}
    const _Float16* giR = gi16;
    const _Float16* giZ = gi16 + 2097152;
    const _Float16* giN = gi16 + 4194304;
    #pragma unroll
    for (int reg = 0; reg < 16; reg++) {
        int row = (reg & 3) + 8 * (reg >> 2) + 4 * half;
        int iloc = (w << 5) + row;
        size_t i = (size_t)Mbase + iloc;
        float g0 = (float)giR[i * 512 + jcg];
        float g1 = (float)giZ[i * 512 + jcg];
        float g2v = (float)giN[i * 512 + jcg];
        float x0 = xs[iloc * 2], x1 = xs[iloc * 2 + 1];
        float r = sigm_f(g0 + p0.x * x0 + p0.y * x1 + accR[reg] + p1.z);
        float u = sigm_f(g1 + p0.z * x0 + p0.w * x1 + accZ[reg] + p1.w);
        float nn = tanh_f(g2v + p1.x * x0 + p1.y * x1 + r * (accN[reg] + p2.x));
        float hold = (float)hin[i * 512 + jcg];
        float hn = (1.f - u) * nn + u * hold;
        hout[i * 512 + jcg] = (_Float16)hn;
        ((float2*)prod)[iloc * 32 + l31] = make_float2(hn * p2.y, hn * p2.z);
    }
    __syncthreads();
    {
        int i = tid >> 1, d = tid & 1;
        float s = 0.f;
        #pragma unroll
        for (int jj = 0; jj < 32; jj++) {
            int jc = (jj + i) & 31;   // skew to avoid bank conflicts
            s += prod[(i * 32 + jc) * 2 + d];
        }
        partial[((size_t)(Mbase + i) * 2 + d) * 16 + by] = s;
    }
}

// ---------------- K3: out_11 = W_out @ h_12 + b_out (direct dot) ----------------
__global__ __launch_bounds__(256) void k3_final(
    const _Float16* __restrict__ h12, const float* __restrict__ W_out,
    const float* __restrict__ b_out, float* __restrict__ dout)
{
    __shared__ float wsh[1024];
    for (int i = threadIdx.x; i < 1024; i += 256) wsh[i] = W_out[i];
    __syncthreads();
    int i = blockIdx.x * 128 + (threadIdx.x >> 1), d = threadIdx.x & 1;
    const f16x8* hp = (const f16x8*)(h12 + (size_t)i * 512);
    const float* wp = wsh + d * 512;
    float s = 0.f;
    #pragma unroll 8
    for (int g = 0; g < 64; g++) {
        f16x8 hv = hp[g];
        #pragma unroll
        for (int e = 0; e < 8; e++) s += (float)hv[e] * wp[g * 8 + e];
    }
    dout[((size_t)i * 12 + 11) * 2 + d] = b_out[d] + s;
}

extern "C" void kernel_launch(void* const* d_in, const int* in_sizes, int n_in,
                              void* d_out, int out_size, void* d_ws, size_t ws_size,
                              hipStream_t stream)
{
    const float* z     = (const float*)d_in[0];
    const float* x     = (const float*)d_in[1];
    const float* x0    = (const float*)d_in[2];
    const float* W_ia  = (const float*)d_in[3];
    const float* b_ia  = (const float*)d_in[4];
    const float* W_h0  = (const float*)d_in[5];
    const float* b_h0  = (const float*)d_in[6];
    const float* W_ih  = (const float*)d_in[7];
    const float* b_ih  = (const float*)d_in[8];
    const float* W_hh  = (const float*)d_in[9];
    const float* b_hh  = (const float*)d_in[10];
    const float* W_out = (const float*)d_in[11];
    const float* b_out = (const float*)d_in[12];
    float* dout = (float*)d_out;

    char* ws = (char*)d_ws;
    _Float16* h16a   = (_Float16*)(ws + 0);          // 4 MiB
    _Float16* h16b   = (_Float16*)(ws + 4194304);    // 4 MiB
    _Float16* gi16   = (_Float16*)(ws + 8388608);    // 3 planes x 2M f16 = 12 MiB
    _Float16* zx16   = (_Float16*)(ws + 20971520);   // 2 MiB
    _Float16* wcat16 = (_Float16*)(ws + 23068672);   // 1 MiB
    _Float16* whh16  = (_Float16*)(ws + 24117248);   // 1.5 MiB
    float*    pk     = (float*)(ws + 25690112);      // 24 KiB
    float*    xbuf   = (float*)(ws + 25714688);      // 32 KiB
    float*    partial= (float*)(ws + 25747456);      // 512 KiB

    k0_prep<<<1024, 256, 0, stream>>>(z, x, x0, W_ia, b_ia, W_ih, W_hh, W_h0,
                                      W_out, b_hh, zx16, wcat16, whh16, pk, xbuf);
    k1_precompute<<<dim3(32, 32), 256, 0, stream>>>(zx16, wcat16, b_h0, b_ih, h16a, gi16);
    for (int t = 0; t < 12; t++) {
        _Float16* hin  = (t & 1) ? h16b : h16a;
        _Float16* hout = (t & 1) ? h16a : h16b;
        k2_step<<<dim3(32, 16), 256, 0, stream>>>(t, hin, hout, whh16, gi16,
                                                  pk, xbuf, partial, dout, b_out);
    }
    k3_final<<<32, 256, 0, stream>>>(h16a, W_out, b_out, dout);
}

// Round 9
// 306.817 us; speedup vs baseline: 1.0073x; 1.0073x over previous
//
#include <hip/hip_runtime.h>
#include <cstdint>
#include <cstddef>

// RNNDec GRU rollout: N=4096, H=512, T=12. R9 = EXACT R5 (proven 295us:
// fp16 single-plane MFMA, gi16 3-plane, partial-exchange k3) + ONE delta:
// vectorized k0 only. Attribution round: R7/R8 shared +13us vs R5 with
// k0vec+k3dot common; this isolates k0vec.

typedef __attribute__((ext_vector_type(8))) _Float16 f16x8;
typedef __attribute__((ext_vector_type(4))) _Float16 f16x4;
typedef __attribute__((ext_vector_type(16))) float floatx16;

__device__ __forceinline__ float sigm_f(float v) { return 1.0f / (1.0f + __expf(-v)); }
__device__ __forceinline__ float tanh_f(float v) { return 2.0f / (1.0f + __expf(-2.0f * v)) - 1.0f; }

__device__ __forceinline__ void async16(void* lds, const void* g) {
    __builtin_amdgcn_global_load_lds(
        (const __attribute__((address_space(1))) void*)g,
        (__attribute__((address_space(3))) void*)lds, 16, 0, 0);
}

// ---------------- K0: casts + packing + a0 (vectorized; ONLY delta vs R5) ----------------
__global__ __launch_bounds__(256) void k0_prep(
    const float* __restrict__ z, const float* __restrict__ x,
    const float* __restrict__ x0, const float* __restrict__ W_ia,
    const float* __restrict__ b_ia, const float* __restrict__ W_ih,
    const float* __restrict__ W_hh, const float* __restrict__ W_h0,
    const float* __restrict__ W_out, const float* __restrict__ b_hh,
    _Float16* __restrict__ zx16, _Float16* __restrict__ wcat16,
    _Float16* __restrict__ whh16, float* __restrict__ pk, float* __restrict__ xbuf)
{
    const int ZXV = 262144;            // 4096*256/4
    const int WCV = 131072;            // 2048*256/4
    const int WHV = 196608;            // 1536*512/4
    const int PKN = 512, XB = 8192;
    const int TOT = ZXV + WCV + WHV + PKN + XB;
    for (int g = blockIdx.x * 256 + threadIdx.x; g < TOT; g += gridDim.x * 256) {
        if (g < ZXV) {
            int i = g >> 6, k = (g & 63) << 2;
            float4 v = (k < 128) ? *(const float4*)(z + (size_t)i * 128 + k)
                                 : *(const float4*)(x + (size_t)i * 128 + (k - 128));
            f16x4 o = {(_Float16)v.x, (_Float16)v.y, (_Float16)v.z, (_Float16)v.w};
            *(f16x4*)(zx16 + (size_t)g * 4) = o;
        } else if (g < ZXV + WCV) {
            int j = (g - ZXV) << 2;
            int n = j >> 8, k = j & 255;
            float4 v;
            if (n < 512) {
                v = *(const float4*)(W_h0 + (size_t)n * 256 + k);
            } else {
                const float* p = W_ih + (size_t)(n - 512) * 258 + k;
                float2 a = *(const float2*)p, b = *(const float2*)(p + 2);
                v = make_float4(a.x, a.y, b.x, b.y);
            }
            f16x4 o = {(_Float16)v.x, (_Float16)v.y, (_Float16)v.z, (_Float16)v.w};
            *(f16x4*)(wcat16 + (size_t)j) = o;
        } else if (g < ZXV + WCV + WHV) {
            int j = (g - ZXV - WCV) << 2;
            float4 v = *(const float4*)(W_hh + (size_t)j);
            f16x4 o = {(_Float16)v.x, (_Float16)v.y, (_Float16)v.z, (_Float16)v.w};
            *(f16x4*)(whh16 + (size_t)j) = o;
        } else if (g < ZXV + WCV + WHV + PKN) {
            int jc = g - ZXV - WCV - WHV;
            float* o = pk + jc * 12;
            o[0] = W_ih[jc * 258 + 256];          o[1] = W_ih[jc * 258 + 257];
            o[2] = W_ih[(512 + jc) * 258 + 256];  o[3] = W_ih[(512 + jc) * 258 + 257];
            o[4] = W_ih[(1024 + jc) * 258 + 256]; o[5] = W_ih[(1024 + jc) * 258 + 257];
            o[6] = b_hh[jc]; o[7] = b_hh[512 + jc]; o[8] = b_hh[1024 + jc];
            o[9] = W_out[jc]; o[10] = W_out[512 + jc]; o[11] = 0.f;
        } else {
            int j = g - ZXV - WCV - WHV - PKN;
            int i = j >> 1, d = j & 1;
            float s = b_ia[d];
            #pragma unroll
            for (int k2 = 0; k2 < 4; k2++) s += x0[i * 4 + k2] * W_ia[d * 4 + k2];
            xbuf[j] = s;
        }
    }
}

// ---------------- K1: h0 (cols 0..511) + gi planes (cols 512..2047), fp16 ----------------
__global__ __launch_bounds__(256) void k1_precompute(
    const _Float16* __restrict__ zx16, const _Float16* __restrict__ wcat16,
    const float* __restrict__ b_h0, const float* __restrict__ b_ih,
    _Float16* __restrict__ h16a, _Float16* __restrict__ gi16)
{
    __shared__ __align__(16) char smem[24576];
    const uint32_t BOFF = 0, AOFF = 8192;
    int tid = threadIdx.x;
    int w = tid >> 6, lane = tid & 63;
    int half = lane >> 5, l31 = lane & 31;
    int rsub = lane >> 3, csub = lane & 7;
    int Mb = blockIdx.x * 128, Nb = blockIdx.y * 64;

    const _Float16* gsrc[6];
    uint32_t ldso[6];
    #pragma unroll
    for (int j = 0; j < 6; j++) {
        int L = w + 4 * j;
        if (L < 16) {
            int r = L * 8 + rsub;
            gsrc[j] = zx16 + (size_t)(Mb + r) * 256 + ((csub ^ (r & 7)) << 3);
            ldso[j] = AOFF + (uint32_t)L * 1024;
        } else {
            int rb = (L - 16) * 8 + rsub;
            gsrc[j] = wcat16 + (size_t)(Nb + rb) * 256 + ((csub ^ (rb & 7)) << 3);
            ldso[j] = BOFF + (uint32_t)(L - 16) * 1024;
        }
    }

    floatx16 acc0 = {0,0,0,0,0,0,0,0,0,0,0,0,0,0,0,0};
    floatx16 acc1 = {0,0,0,0,0,0,0,0,0,0,0,0,0,0,0,0};

    for (int kc = 0; kc < 4; kc++) {
        #pragma unroll
        for (int j = 0; j < 6; j++) async16(smem + ldso[j], gsrc[j] + kc * 64);
        __syncthreads();
        #pragma unroll
        for (int ks = 0; ks < 4; ks++) {
            int ch = ks * 2 + half;
            int ar = (w << 5) | l31;
            f16x8 a = *(const f16x8*)(smem + AOFF + ((uint32_t)ar << 7) + ((uint32_t)(ch ^ (ar & 7)) << 4));
            uint32_t sw = (uint32_t)(ch ^ (l31 & 7)) << 4;
            f16x8 b0 = *(const f16x8*)(smem + BOFF + ((uint32_t)l31 << 7) + sw);
            f16x8 b1 = *(const f16x8*)(smem + BOFF + ((uint32_t)(32 + l31) << 7) + sw);
            acc0 = __builtin_amdgcn_mfma_f32_32x32x16_f16(a, b0, acc0, 0, 0, 0);
            acc1 = __builtin_amdgcn_mfma_f32_32x32x16_f16(a, b1, acc1, 0, 0, 0);
        }
        __syncthreads();
    }

    #pragma unroll
    for (int nt = 0; nt < 2; nt++) {
        int ncol = Nb + nt * 32 + l31;
        floatx16 acc = nt ? acc1 : acc0;
        #pragma unroll
        for (int reg = 0; reg < 16; reg++) {
            int row = (reg & 3) + 8 * (reg >> 2) + 4 * half;
            size_t i = (size_t)Mb + (w << 5) + row;
            float v = acc[reg];
            if (ncol < 512) {
                h16a[i * 512 + ncol] = (_Float16)(v + b_h0[ncol]);
            } else {
                int c = ncol - 512;
                int g = c >> 9, jc = c & 511;
                gi16[(size_t)g * 2097152 + i * 512 + jc] = (_Float16)(v + b_ih[c]);
            }
        }
    }
}

// ---------------- K2: one GRU step (R5 structure, byte-identical) ----------------
// Tile 128m x (32 jc x 3 gates). grid (32,16), 256 thr = 4 waves.
__global__ __launch_bounds__(256) void k2_step(
    int t,
    const _Float16* __restrict__ hin, _Float16* __restrict__ hout,
    const _Float16* __restrict__ whh16, const _Float16* __restrict__ gi16,
    const float* __restrict__ pk, const float* __restrict__ xbuf,
    float* __restrict__ partial, float* __restrict__ dout,
    const float* __restrict__ b_out)
{
    __shared__ __align__(16) char smem[46080];
    const uint32_t BOFF = 0, AOFF = 12288, PROD = 12288, XS = 45056;
    int tid = threadIdx.x;
    int bx = blockIdx.x, by = blockIdx.y;
    int Mbase = bx * 128, Jbase = by * 32;
    int w = tid >> 6, lane = tid & 63;
    int half = lane >> 5, l31 = lane & 31;
    int rsub = lane >> 3, csub = lane & 7;
    float* xs = (float*)(smem + XS);  // [128][2]

    // staging: A = 16 slots of 8 rows x 64 fp16; B = 12 slots (96 rows: g*32+jin)
    const _Float16* gsrc[7];
    uint32_t ldso[7];
    #pragma unroll
    for (int j = 0; j < 7; j++) {
        int L = w + 4 * j;   // 0..27
        if (L < 16) {
            int r = L * 8 + rsub;
            gsrc[j] = hin + (size_t)(Mbase + r) * 512 + ((csub ^ (r & 7)) << 3);
            ldso[j] = AOFF + (uint32_t)L * 1024;
        } else {
            int rb = (L - 16) * 8 + rsub;   // 0..95: rb = g*32 + jin
            int g = rb >> 5, jin = rb & 31;
            gsrc[j] = whh16 + (size_t)(g * 512 + Jbase + jin) * 512 + ((csub ^ (rb & 7)) << 3);
            ldso[j] = BOFF + (uint32_t)(L - 16) * 1024;
        }
    }

    // prologue: x_t for this block's 128 samples (and write out_{t-1})
    {
        int i = tid >> 1, d = tid & 1;
        float v;
        if (t == 0) {
            v = xbuf[(size_t)(Mbase + i) * 2 + d];
        } else {
            const float4* p = (const float4*)(partial + ((size_t)(Mbase + i) * 2 + d) * 16);
            float4 a = p[0], b = p[1], c = p[2], e = p[3];
            v = b_out[d] + a.x + a.y + a.z + a.w + b.x + b.y + b.z + b.w
                         + c.x + c.y + c.z + c.w + e.x + e.y + e.z + e.w;
            if (by == 0) dout[((size_t)(Mbase + i) * 12 + (t - 1)) * 2 + d] = v;
        }
        xs[i * 2 + d] = v;
    }

    floatx16 accR = {0,0,0,0,0,0,0,0,0,0,0,0,0,0,0,0};
    floatx16 accZ = {0,0,0,0,0,0,0,0,0,0,0,0,0,0,0,0};
    floatx16 accN = {0,0,0,0,0,0,0,0,0,0,0,0,0,0,0,0};

    for (int kc = 0; kc < 8; kc++) {
        #pragma unroll
        for (int j = 0; j < 7; j++) async16(smem + ldso[j], gsrc[j] + kc * 64);
        __syncthreads();
        #pragma unroll
        for (int ks = 0; ks < 4; ks++) {
            int ch = ks * 2 + half;
            int ar = (w << 5) | l31;
            f16x8 a = *(const f16x8*)(smem + AOFF + ((uint32_t)ar << 7) + ((uint32_t)(ch ^ (ar & 7)) << 4));
            uint32_t sw = (uint32_t)(ch ^ (l31 & 7)) << 4;
            f16x8 b0 = *(const f16x8*)(smem + BOFF + ((uint32_t)l31 << 7) + sw);
            f16x8 b1 = *(const f16x8*)(smem + BOFF + ((uint32_t)(32 + l31) << 7) + sw);
            f16x8 b2 = *(const f16x8*)(smem + BOFF + ((uint32_t)(64 + l31) << 7) + sw);
            accR = __builtin_amdgcn_mfma_f32_32x32x16_f16(a, b0, accR, 0, 0, 0);
            accZ = __builtin_amdgcn_mfma_f32_32x32x16_f16(a, b1, accZ, 0, 0, 0);
            accN = __builtin_amdgcn_mfma_f32_32x32x16_f16(a, b2, accN, 0, 0, 0);
        }
        __syncthreads();
    }

    // epilogue: gates + state update; out-partials in LDS (reuse A/B region)
    float* prod = (float*)(smem + PROD);  // [128][32][2] fp32 = 32 KB
    int jcg = Jbase + l31;
    const float4* pkp = (const float4*)(pk + (size_t)jcg * 12);
    float4 p0 = pkp[0], p1 = pkp[1], p2 = pkp[2];
    // p0={wxr0,wxr1,wxz0,wxz1} p1={wxn0,wxn1,bhr,bhz} p2={bhn,wo0,wo1,-}
    const _Float16* giR = gi16;
    const _Float16* giZ = gi16 + 2097152;
    const _Float16* giN = gi16 + 4194304;
    #pragma unroll
    for (int reg = 0; reg < 16; reg++) {
        int row = (reg & 3) + 8 * (reg >> 2) + 4 * half;
        int iloc = (w << 5) + row;
        size_t i = (size_t)Mbase + iloc;
        float g0 = (float)giR[i * 512 + jcg];
        float g1 = (float)giZ[i * 512 + jcg];
        float g2v = (float)giN[i * 512 + jcg];
        float x0 = xs[iloc * 2], x1 = xs[iloc * 2 + 1];
        float r = sigm_f(g0 + p0.x * x0 + p0.y * x1 + accR[reg] + p1.z);
        float u = sigm_f(g1 + p0.z * x0 + p0.w * x1 + accZ[reg] + p1.w);
        float nn = tanh_f(g2v + p1.x * x0 + p1.y * x1 + r * (accN[reg] + p2.x));
        float hold = (float)hin[i * 512 + jcg];
        float hn = (1.f - u) * nn + u * hold;
        hout[i * 512 + jcg] = (_Float16)hn;
        ((float2*)prod)[iloc * 32 + l31] = make_float2(hn * p2.y, hn * p2.z);
    }
    __syncthreads();
    {
        int i = tid >> 1, d = tid & 1;
        float s = 0.f;
        #pragma unroll
        for (int jj = 0; jj < 32; jj++) {
            int jc = (jj + i) & 31;   // skew to avoid bank conflicts
            s += prod[(i * 32 + jc) * 2 + d];
        }
        partial[((size_t)(Mbase + i) * 2 + d) * 16 + by] = s;
    }
}

// ---------------- K3: final output out_11 (R5 partial-based) ----------------
__global__ __launch_bounds__(256) void k3_final(
    const float* __restrict__ partial, const float* __restrict__ b_out,
    float* __restrict__ dout)
{
    int gid = blockIdx.x * 256 + threadIdx.x;
    if (gid < 8192) {
        int i = gid >> 1, d = gid & 1;
        const float4* p = (const float4*)(partial + ((size_t)i * 2 + d) * 16);
        float4 a = p[0], b = p[1], c = p[2], e = p[3];
        float v = b_out[d] + a.x + a.y + a.z + a.w + b.x + b.y + b.z + b.w
                           + c.x + c.y + c.z + c.w + e.x + e.y + e.z + e.w;
        dout[((size_t)i * 12 + 11) * 2 + d] = v;
    }
}

extern "C" void kernel_launch(void* const* d_in, const int* in_sizes, int n_in,
                              void* d_out, int out_size, void* d_ws, size_t ws_size,
                              hipStream_t stream)
{
    const float* z     = (const float*)d_in[0];
    const float* x     = (const float*)d_in[1];
    const float* x0    = (const float*)d_in[2];
    const float* W_ia  = (const float*)d_in[3];
    const float* b_ia  = (const float*)d_in[4];
    const float* W_h0  = (const float*)d_in[5];
    const float* b_h0  = (const float*)d_in[6];
    const float* W_ih  = (const float*)d_in[7];
    const float* b_ih  = (const float*)d_in[8];
    const float* W_hh  = (const float*)d_in[9];
    const float* b_hh  = (const float*)d_in[10];
    const float* W_out = (const float*)d_in[11];
    const float* b_out = (const float*)d_in[12];
    float* dout = (float*)d_out;

    char* ws = (char*)d_ws;
    _Float16* h16a   = (_Float16*)(ws + 0);          // 4 MiB
    _Float16* h16b   = (_Float16*)(ws + 4194304);    // 4 MiB
    _Float16* gi16   = (_Float16*)(ws + 8388608);    // 3 planes x 4096*512 fp16 = 12 MiB
    _Float16* zx16   = (_Float16*)(ws + 20971520);   // 2 MiB
    _Float16* wcat16 = (_Float16*)(ws + 23068672);   // 1 MiB
    _Float16* whh16  = (_Float16*)(ws + 24117248);   // 1.5 MiB
    float*    pk     = (float*)(ws + 25690112);      // 24 KiB
    float*    xbuf   = (float*)(ws + 25714688);      // 32 KiB
    float*    partial= (float*)(ws + 25747456);      // 512 KiB

    k0_prep<<<1024, 256, 0, stream>>>(z, x, x0, W_ia, b_ia, W_ih, W_hh, W_h0,
                                      W_out, b_hh, zx16, wcat16, whh16, pk, xbuf);
    k1_precompute<<<dim3(32, 32), 256, 0, stream>>>(zx16, wcat16, b_h0, b_ih, h16a, gi16);
    for (int t = 0; t < 12; t++) {
        _Float16* hin  = (t & 1) ? h16b : h16a;
        _Float16* hout = (t & 1) ? h16a : h16b;
        k2_step<<<dim3(32, 16), 256, 0, stream>>>(t, hin, hout, whh16, gi16,
                                                  pk, xbuf, partial, dout, b_out);
    }
    k3_final<<<32, 256, 0, stream>>>(partial, b_out, dout);
}